// Round 1
// 262.191 us; speedup vs baseline: 1.0375x; 1.0375x over previous
//
#include <hip/hip_runtime.h>
#include <hip/hip_fp16.h>

#define N_NODES 50000
#define N_EDGES 800000
#define NBKT 196            // ceil(50000 / 256) coarse buckets (dst >> 8)
#define EPB_BIN 4096        // edges per binning block
#define NB_BIN ((N_EDGES + EPB_BIN - 1) / EPB_BIN)   // 196
#define NB_EL 196           // ceil(50000/256) blocks for el9p role
#define NB_PW 48            // 64*192/256 blocks for prepW role

typedef _Float16 half8 __attribute__((ext_vector_type(8)));
typedef float f32x4 __attribute__((ext_vector_type(4)));

static __device__ __forceinline__ float lrelu(float x) { return fmaxf(x, 0.2f * x); }

// ---------------- fused front kernel: cntb | el9p | prepW | prepA -----------
// All four roles are mutually independent; fusing fills the machine
// (196+196+48+1 = 441 blocks) and removes 3 launch slots.
__global__ void __launch_bounds__(256) k_front(const int* __restrict__ dst,
                                               int* __restrict__ bcnt,
                                               const float* __restrict__ x,
                                               const float* __restrict__ W1,
                                               const float* __restrict__ al1,
                                               const float* __restrict__ ar1,
                                               float* __restrict__ xp,
                                               float* __restrict__ er,
                                               const float* __restrict__ W2,
                                               __half* __restrict__ Wt16,
                                               const float* __restrict__ al2,
                                               const float* __restrict__ ar2,
                                               float* __restrict__ Wa2,
                                               float* __restrict__ Wr2) {
    __shared__ int lcnt[NBKT];
    __shared__ float sWa[9 * 3];
    __shared__ float sWr[9 * 3];
    const int t = threadIdx.x;
    const int b = blockIdx.x;

    if (b < NB_BIN) {
        // ---- role: bucket counts ----
        const int e0 = b * EPB_BIN;
        for (int i = t; i < NBKT; i += 256) lcnt[i] = 0;
        __syncthreads();
#pragma unroll
        for (int i = 0; i < 16; ++i) {
            const int e = e0 + i * 256 + t;
            if (e < N_EDGES) atomicAdd(&lcnt[dst[e] >> 8], 1);
        }
        __syncthreads();
        for (int i = t; i < NBKT; i += 256)
            if (lcnt[i]) atomicAdd(&bcnt[i], lcnt[i]);
        return;
    }
    if (b < NB_BIN + NB_EL) {
        // ---- role: layer-1 packed features + er ----
        if (t < 27) {
            const int h = t / 9, k = t % 9;
            float sa = 0.f, sr = 0.f;
            for (int f = 0; f < 64; ++f) {
                const float w = W1[k * 192 + h * 64 + f];
                sa += w * al1[h * 64 + f];
                sr += w * ar1[h * 64 + f];
            }
            sWa[k * 3 + h] = sa;
            sWr[k * 3 + h] = sr;
        }
        __syncthreads();
        const int n = (b - NB_BIN) * 256 + t;
        if (n >= N_NODES) return;
        const float* __restrict__ xr = x + (size_t)n * 9;
        float xv[9];
        float a0 = 0.f, a1 = 0.f, a2 = 0.f, r0 = 0.f, r1 = 0.f, r2 = 0.f;
#pragma unroll
        for (int k = 0; k < 9; ++k) {
            xv[k] = xr[k];
            a0 += xv[k] * sWa[k * 3 + 0];
            a1 += xv[k] * sWa[k * 3 + 1];
            a2 += xv[k] * sWa[k * 3 + 2];
            r0 += xv[k] * sWr[k * 3 + 0];
            r1 += xv[k] * sWr[k * 3 + 1];
            r2 += xv[k] * sWr[k * 3 + 2];
        }
        float* __restrict__ xo = xp + (size_t)n * 12;
        *reinterpret_cast<float4*>(xo) = make_float4(xv[0], xv[1], xv[2], xv[3]);
        *reinterpret_cast<float4*>(xo + 4) = make_float4(xv[4], xv[5], xv[6], xv[7]);
        *reinterpret_cast<float4*>(xo + 8) = make_float4(xv[8], a0, a1, a2);
        *reinterpret_cast<float4*>(er + (size_t)n * 4) = make_float4(r0, r1, r2, 0.f);
        return;
    }
    if (b < NB_BIN + NB_EL + NB_PW) {
        // ---- role: W2 -> fp16 effective-transpose table ----
        const int idx = (b - (NB_BIN + NB_EL)) * 256 + t;
        if (idx < 64 * 192) {
            const int n = idx / 192, ke = idx % 192;
            Wt16[idx] = __float2half(W2[(ke & 63) * 192 + (ke >> 6) * 64 + n]);
        }
        return;
    }
    // ---- role: Wa2/Wr2 precompute ----
    if (t < 192) {
        const int h = t >> 6, k = t & 63;
        float sa = 0.f, sr = 0.f;
        for (int f = 0; f < 64; ++f) {
            const float w = W2[k * 192 + h * 64 + f];
            sa += w * al2[h * 64 + f];
            sr += w * ar2[h * 64 + f];
        }
        Wa2[k * 4 + h] = sa;
        Wr2[k * 4 + h] = sr;
        if (h == 0) { Wa2[k * 4 + 3] = 0.f; Wr2[k * 4 + 3] = 0.f; }
    }
}

// ---------------- bin edges (bucket scan inlined; k_scanb deleted) ----------
__global__ void __launch_bounds__(256) k_bin(const int* __restrict__ src,
                                             const int* __restrict__ dst,
                                             const int* __restrict__ bcnt,
                                             int* __restrict__ bfill,
                                             unsigned int* __restrict__ stage) {
    __shared__ int lcnt[NBKT];
    __shared__ int gb[NBKT];
    __shared__ int lf[NBKT];
    __shared__ int sscan[256];
    __shared__ int sbase[256];
    const int t = threadIdx.x;
    const int e0 = blockIdx.x * EPB_BIN;
    // inline exclusive scan of bucket counts
    const int bv = (t < NBKT) ? bcnt[t] : 0;
    sscan[t] = bv;
    if (t < NBKT) lcnt[t] = 0;
    __syncthreads();
    for (int off = 1; off < 256; off <<= 1) {
        const int u = (t >= off) ? sscan[t - off] : 0;
        __syncthreads();
        sscan[t] += u;
        __syncthreads();
    }
    sbase[t] = sscan[t] - bv;
    int dcache[16];
#pragma unroll
    for (int i = 0; i < 16; ++i) {
        const int e = e0 + i * 256 + t;
        if (e < N_EDGES) {
            const int d = dst[e];
            dcache[i] = d;
            atomicAdd(&lcnt[d >> 8], 1);
        } else dcache[i] = -1;
    }
    __syncthreads();
    for (int i = t; i < NBKT; i += 256) {
        gb[i] = sbase[i] + atomicAdd(&bfill[i], lcnt[i]);
        lf[i] = 0;
    }
    __syncthreads();
#pragma unroll
    for (int i = 0; i < 16; ++i) {
        const int e = e0 + i * 256 + t;
        if (e < N_EDGES) {
            const int d = dcache[i];
            const int bk = d >> 8;
            const int r = atomicAdd(&lf[bk], 1);
            stage[gb[bk] + r] = (unsigned int)src[e] | ((unsigned int)(d & 255) << 16);
        }
    }
}

// ---------------- per bucket scatter (bucket scan inlined) ------------------
__global__ void __launch_bounds__(256) k_bscatter2(const unsigned int* __restrict__ stage,
                                                   const int* __restrict__ bcnt,
                                                   int* __restrict__ rowp,
                                                   int* __restrict__ col) {
    __shared__ int lcnt[256];
    __shared__ int lpos[256];
    __shared__ int sexc[256];
    __shared__ int sscan[256];
    const int t = threadIdx.x;
    const int b = blockIdx.x;
    const int n0 = b << 8;
    // inline inclusive scan of bucket counts -> base/end for this bucket
    const int bv = (t < NBKT) ? bcnt[t] : 0;
    sscan[t] = bv;
    lcnt[t] = 0;
    __syncthreads();
    for (int off = 1; off < 256; off <<= 1) {
        const int u = (t >= off) ? sscan[t - off] : 0;
        __syncthreads();
        sscan[t] += u;
        __syncthreads();
    }
    const int base = (b == 0) ? 0 : sscan[b - 1];
    const int end = sscan[b];

    for (int j = base + t; j < end; j += 256)
        atomicAdd(&lcnt[(stage[j] >> 16) & 255], 1);
    __syncthreads();
    const int v = lcnt[t];
    lpos[t] = v;
    __syncthreads();
    for (int off = 1; off < 256; off <<= 1) {
        const int u = (t >= off) ? lpos[t - off] : 0;
        __syncthreads();
        lpos[t] += u;
        __syncthreads();
    }
    sexc[t] = lpos[t] - v;
    if (n0 + t < N_NODES) rowp[n0 + t] = base + sexc[t];
    if (b == NBKT - 1 && t == 0) rowp[N_NODES] = N_EDGES;
    lcnt[t] = 0;   // reuse as fill counters
    __syncthreads();
    for (int j = base + t; j < end; j += 256) {
        const unsigned int e = stage[j];
        const int local = (int)(e >> 16) & 255;
        const int r = atomicAdd(&lcnt[local], 1);
        col[base + sexc[local] + r] = (int)(e & 0xFFFFu);
    }
}

// ---------------- L1 aggregation: lane-per-edge, quarter-wave per node -------
__global__ void __launch_bounds__(256) k_aggw9(const float* __restrict__ xp,
                                               const float* __restrict__ er,
                                               const int* __restrict__ rowp,
                                               const int* __restrict__ col,
                                               float* __restrict__ agg) {
    const int tid = threadIdx.x;
    const int wv = tid >> 6;
    const int lane = tid & 63;
    const int q = lane >> 4;            // node slot within wave
    const int ql = lane & 15;           // lane within quarter
    const int n = (blockIdx.x * 4 + wv) * 4 + q;   // grid exact: 3125*4*4 = 50000
    const int jb = rowp[n], je = rowp[n + 1];
    const float4 er4 = *reinterpret_cast<const float4*>(er + (size_t)n * 4);

    float acc[27];
#pragma unroll
    for (int j = 0; j < 27; ++j) acc[j] = 0.f;
    float sw0 = 0.f, sw1 = 0.f, sw2 = 0.f;

    for (int e = jb + ql; e < je; e += 16) {
        const int s = col[e];
        const float* __restrict__ row = xp + (size_t)s * 12;
        const float4 xa = *reinterpret_cast<const float4*>(row);
        const float4 xb = *reinterpret_cast<const float4*>(row + 4);
        const float4 xc = *reinterpret_cast<const float4*>(row + 8);
        const float w0 = __expf(lrelu(xc.y + er4.x));
        const float w1 = __expf(lrelu(xc.z + er4.y));
        const float w2 = __expf(lrelu(xc.w + er4.z));
        sw0 += w0; sw1 += w1; sw2 += w2;
        const float xv[9] = {xa.x, xa.y, xa.z, xa.w, xb.x, xb.y, xb.z, xb.w, xc.x};
#pragma unroll
        for (int k = 0; k < 9; ++k) {
            acc[0 + k]  += w0 * xv[k];
            acc[9 + k]  += w1 * xv[k];
            acc[18 + k] += w2 * xv[k];
        }
    }
#pragma unroll
    for (int off = 1; off < 16; off <<= 1) {
        sw0 += __shfl_xor(sw0, off);
        sw1 += __shfl_xor(sw1, off);
        sw2 += __shfl_xor(sw2, off);
#pragma unroll
        for (int j = 0; j < 27; ++j) acc[j] += __shfl_xor(acc[j], off);
    }
    if (ql == 0) {
        const bool has = (je > jb);
        const float i0 = has ? 1.f / sw0 : 0.f;
        const float i1 = has ? 1.f / sw1 : 0.f;
        const float i2 = has ? 1.f / sw2 : 0.f;
        float o[28];
#pragma unroll
        for (int k = 0; k < 9; ++k) {
            o[k] = acc[k] * i0;
            o[9 + k] = acc[9 + k] * i1;
            o[18 + k] = acc[18 + k] * i2;
        }
        o[27] = 0.f;
        float4* __restrict__ ao = reinterpret_cast<float4*>(agg + (size_t)n * 28);
#pragma unroll
        for (int v = 0; v < 7; ++v)
            ao[v] = make_float4(o[4 * v], o[4 * v + 1], o[4 * v + 2], o[4 * v + 3]);
    }
}

// ---------------- L2 aggregation v3: dwordx4 gather, 8 edges/wave-load -------
// TA model: old v1 = 32 lane-addresses per 128B row -> 41.7us floor (matches
// measured 41.5). half8 per lane -> 8 addresses/edge, 4x less TA work.
// Cost: 24 accums/lane + 3-stage reduce (~144 instr/node, ~0.3us device-wide).
// Gather software-pipelined 2-deep (issue chunk k+1 before consuming chunk k).
__global__ void __launch_bounds__(256) k_aggw64(const __half* __restrict__ x,
                                                const float* __restrict__ el,
                                                const float* __restrict__ er,
                                                const int* __restrict__ rowp,
                                                const int* __restrict__ col,
                                                __half* __restrict__ agg) {
    const int wv = threadIdx.x >> 6;
    const int lane = threadIdx.x & 63;
    const int n = blockIdx.x * 4 + wv;          // grid exact
    const int jb = rowp[n], je = rowp[n + 1];

    __shared__ float wbuf[4][3][68];
    __shared__ int cbuf[4][68];
    const float4 er4 = *reinterpret_cast<const float4*>(er + (size_t)n * 4);
    const int eg = lane >> 3;        // edge group 0..7 within chunk
    const int fo = lane & 7;         // feature octet: feats fo*8 .. fo*8+7

    float a0[8], a1[8], a2[8];
#pragma unroll
    for (int j = 0; j < 8; ++j) { a0[j] = 0.f; a1[j] = 0.f; a2[j] = 0.f; }
    float sw0 = 0.f, sw1 = 0.f, sw2 = 0.f;

    for (int c0 = jb; c0 < je; c0 += 64) {
        const int cnt = min(64, je - c0);
        float w0 = 0.f, w1 = 0.f, w2 = 0.f;
        if (lane < cnt) {
            const int s = col[c0 + lane];
            cbuf[wv][lane] = s;
            const float4 e4 = *reinterpret_cast<const float4*>(el + (size_t)s * 4);
            w0 = __expf(lrelu(e4.x + er4.x));
            w1 = __expf(lrelu(e4.y + er4.y));
            w2 = __expf(lrelu(e4.z + er4.z));
            wbuf[wv][0][lane] = w0;
            wbuf[wv][1][lane] = w1;
            wbuf[wv][2][lane] = w2;
        }
        sw0 += w0; sw1 += w1; sw2 += w2;

        // pipelined gather over 8-edge chunks
        int ei = eg;
        const int sP = cbuf[wv][min(ei, cnt - 1)];
        half8 xv = *reinterpret_cast<const half8*>(x + (size_t)sP * 64 + fo * 8);
        for (int e0 = 8; e0 < cnt; e0 += 8) {
            const int ei2 = e0 + eg;
            const int sN = cbuf[wv][min(ei2, cnt - 1)];
            const half8 xn = *reinterpret_cast<const half8*>(x + (size_t)sN * 64 + fo * 8);
            const bool val = (ei < cnt);
            const float we0 = val ? wbuf[wv][0][ei] : 0.f;
            const float we1 = val ? wbuf[wv][1][ei] : 0.f;
            const float we2 = val ? wbuf[wv][2][ei] : 0.f;
#pragma unroll
            for (int j = 0; j < 8; ++j) {
                const float xf = (float)xv[j];
                a0[j] += we0 * xf;
                a1[j] += we1 * xf;
                a2[j] += we2 * xf;
            }
            xv = xn;
            ei = ei2;
        }
        {
            const bool val = (ei < cnt);
            const float we0 = val ? wbuf[wv][0][ei] : 0.f;
            const float we1 = val ? wbuf[wv][1][ei] : 0.f;
            const float we2 = val ? wbuf[wv][2][ei] : 0.f;
#pragma unroll
            for (int j = 0; j < 8; ++j) {
                const float xf = (float)xv[j];
                a0[j] += we0 * xf;
                a1[j] += we1 * xf;
                a2[j] += we2 * xf;
            }
        }
    }
    // reduce over the 8 edge groups (lanes differing in bits 3..5)
#pragma unroll
    for (int off = 8; off < 64; off <<= 1) {
#pragma unroll
        for (int j = 0; j < 8; ++j) {
            a0[j] += __shfl_xor(a0[j], off);
            a1[j] += __shfl_xor(a1[j], off);
            a2[j] += __shfl_xor(a2[j], off);
        }
    }
#pragma unroll
    for (int off = 32; off > 0; off >>= 1) {
        sw0 += __shfl_xor(sw0, off);
        sw1 += __shfl_xor(sw1, off);
        sw2 += __shfl_xor(sw2, off);
    }
    if (eg == 0) {
        __half* __restrict__ ao = agg + (size_t)n * 192 + fo * 8;
        if (je > jb) {
            const float i0 = 1.f / sw0, i1 = 1.f / sw1, i2 = 1.f / sw2;
            half8 h0, h1, h2;
#pragma unroll
            for (int j = 0; j < 8; ++j) {
                h0[j] = (_Float16)(a0[j] * i0);
                h1[j] = (_Float16)(a1[j] * i1);
                h2[j] = (_Float16)(a2[j] * i2);
            }
            *reinterpret_cast<half8*>(ao) = h0;
            *reinterpret_cast<half8*>(ao + 64) = h1;
            *reinterpret_cast<half8*>(ao + 128) = h2;
        } else {
            half8 z;
#pragma unroll
            for (int j = 0; j < 8; ++j) z[j] = (_Float16)0.f;
            *reinterpret_cast<half8*>(ao) = z;
            *reinterpret_cast<half8*>(ao + 64) = z;
            *reinterpret_cast<half8*>(ao + 128) = z;
        }
    }
}

// ---------------- layer-1 post-agg GEMM + fused el2/er2 ----------------------
template <int KE, int AS, int HOFF>
__global__ void __launch_bounds__(192) k_gemm2(const float* __restrict__ agg,
                                               const float* __restrict__ W,
                                               const float* __restrict__ bias,
                                               const float* __restrict__ Wa2,
                                               const float* __restrict__ Wr2,
                                               __half* __restrict__ hout,
                                               float* __restrict__ el,
                                               float* __restrict__ er) {
    const int NPB = 16;
    const int h = threadIdx.x >> 6;
    const int c = threadIdx.x & 63;
    float wreg[KE];
#pragma unroll
    for (int k = 0; k < KE; ++k) wreg[k] = W[k * 192 + h * 64 + c];

    __shared__ float At[NPB * AS];
    __shared__ float part[3][NPB][64];
    const int nbase = blockIdx.x * NPB;         // 3125 * 16 = 50000 exact

    const float4* __restrict__ src4 =
        reinterpret_cast<const float4*>(agg + (size_t)nbase * AS);
    float4* At4 = reinterpret_cast<float4*>(At);
    for (int idx = threadIdx.x; idx < NPB * AS / 4; idx += 192) At4[idx] = src4[idx];
    __syncthreads();

#pragma unroll
    for (int i = 0; i < NPB; ++i) {
        const float* __restrict__ ar = At + i * AS + h * HOFF;
        float acc = 0.f;
#pragma unroll
        for (int k = 0; k < KE; ++k) acc += ar[k] * wreg[k];
        part[h][i][c] = acc;
    }
    __syncthreads();
    const int lane = threadIdx.x & 63;
    const float4 wa = *reinterpret_cast<const float4*>(Wa2 + lane * 4);
    const float4 wr = *reinterpret_cast<const float4*>(Wr2 + lane * 4);
    for (int idx = threadIdx.x; idx < NPB * 64; idx += 192) {
        const int i = idx >> 6, cc = idx & 63;  // cc == lane (192 % 64 == 0)
        const float v = part[0][i][cc] + part[1][i][cc] + part[2][i][cc]
                      + bias[cc] + bias[64 + cc] + bias[128 + cc];
        hout[(size_t)(nbase + i) * 64 + cc] = __float2half(v);
        float e0 = v * wa.x, e1 = v * wa.y, e2 = v * wa.z;
        float r0 = v * wr.x, r1 = v * wr.y, r2 = v * wr.z;
#pragma unroll
        for (int off = 32; off > 0; off >>= 1) {
            e0 += __shfl_xor(e0, off); e1 += __shfl_xor(e1, off); e2 += __shfl_xor(e2, off);
            r0 += __shfl_xor(r0, off); r1 += __shfl_xor(r1, off); r2 += __shfl_xor(r2, off);
        }
        if (lane == 0) {
            *reinterpret_cast<float4*>(el + (size_t)(nbase + i) * 4) = make_float4(e0, e1, e2, 0.f);
            *reinterpret_cast<float4*>(er + (size_t)(nbase + i) * 4) = make_float4(r0, r1, r2, 0.f);
        }
    }
}

// ---------------- layer-2 GEMM via MFMA, fragment-direct ---------------------
__global__ void __launch_bounds__(256) k_gemm3m(const __half* __restrict__ agg,
                                                const __half* __restrict__ Wt,
                                                const float* __restrict__ bias,
                                                __half* __restrict__ hout) {
    const int wv = threadIdx.x >> 6;
    const int lane = threadIdx.x & 63;
    const int quad = lane >> 4;
    const int t16 = lane & 15;
    const int nwave = blockIdx.x * 64 + wv * 16;

    const int arow = min(nwave + t16, N_NODES - 1);
    half8 a[6];
#pragma unroll
    for (int kb = 0; kb < 6; ++kb)
        a[kb] = *reinterpret_cast<const half8*>(agg + (size_t)arow * 192 + kb * 32 + quad * 8);

    float bs[4];
#pragma unroll
    for (int nt = 0; nt < 4; ++nt) {
        const int c = nt * 16 + t16;
        bs[nt] = bias[c] + bias[64 + c] + bias[128 + c];
    }

#pragma unroll
    for (int nt = 0; nt < 4; ++nt) {
        const __half* __restrict__ bt = Wt + (size_t)(nt * 16 + t16) * 192 + quad * 8;
        f32x4 acc = {0.f, 0.f, 0.f, 0.f};
#pragma unroll
        for (int kb = 0; kb < 6; ++kb) {
            const half8 bfrag = *reinterpret_cast<const half8*>(bt + kb * 32);
            acc = __builtin_amdgcn_mfma_f32_16x16x32_f16(a[kb], bfrag, acc, 0, 0, 0);
        }
        const int c = nt * 16 + t16;
#pragma unroll
        for (int r = 0; r < 4; ++r) {
            const int node = nwave + quad * 4 + r;
            if (node < N_NODES)
                hout[(size_t)node * 64 + c] = __float2half(acc[r] + bs[nt]);
        }
    }
}

// ---------------- layer 3: packed feat3p[N][12]={el3[0..2],feat[0..5],pad} ---
__global__ void __launch_bounds__(256) k_feat3(const __half* __restrict__ x,
                                               const float* __restrict__ W3,
                                               const float* __restrict__ al3,
                                               const float* __restrict__ ar3,
                                               float* __restrict__ feat3p,
                                               float* __restrict__ er3) {
    __shared__ float Wl[64 * 6];
    __shared__ float Wal[64 * 3];
    __shared__ float Wrl[64 * 3];
    __shared__ float xl[32 * 68];
    const int t = threadIdx.x;
    const int n0 = blockIdx.x * 32;
    const int nvalid = min(32, N_NODES - n0);
    for (int idx = t; idx < 384; idx += 256) Wl[idx] = W3[idx];
    if (t < 192) {
        const int k = t & 63, h = t >> 6;
        Wal[k * 3 + h] = W3[k * 6 + h * 2] * al3[h * 2] + W3[k * 6 + h * 2 + 1] * al3[h * 2 + 1];
        Wrl[k * 3 + h] = W3[k * 6 + h * 2] * ar3[h * 2] + W3[k * 6 + h * 2 + 1] * ar3[h * 2 + 1];
    }
    for (int idx = t; idx < nvalid * 64; idx += 256)
        xl[(idx >> 6) * 68 + (idx & 63)] = __half2float(x[(size_t)n0 * 64 + idx]);
    __syncthreads();

    const int i = t >> 3;
    const int slot = t & 7;
    if (i < nvalid && slot < 6) {
        float acc = 0.f;
#pragma unroll
        for (int k4 = 0; k4 < 16; ++k4) {
            const float4 xv = *reinterpret_cast<const float4*>(&xl[i * 68 + 4 * k4]);
            acc += Wl[(4 * k4 + 0) * 6 + slot] * xv.x;
            acc += Wl[(4 * k4 + 1) * 6 + slot] * xv.y;
            acc += Wl[(4 * k4 + 2) * 6 + slot] * xv.z;
            acc += Wl[(4 * k4 + 3) * 6 + slot] * xv.w;
        }
        feat3p[(size_t)(n0 + i) * 12 + 3 + slot] = acc;   // feat at offsets 3..8
    }
    if (t < 192) {
        const int ii = t / 6, ss = t % 6;
        if (ii < nvalid) {
            const int hh = (ss < 3) ? ss : ss - 3;
            const float* __restrict__ wt = (ss < 3) ? Wal : Wrl;
            float acc = 0.f;
#pragma unroll 4
            for (int k = 0; k < 64; ++k) acc += xl[ii * 68 + k] * wt[k * 3 + hh];
            if (ss < 3) feat3p[(size_t)(n0 + ii) * 12 + hh] = acc;   // el3 at 0..2
            else        er3[(size_t)(n0 + ii) * 4 + hh] = acc;
        }
    }
}

// ---------------- layer-3 aggregation v2: lane-per-edge (aggw9 pattern) ------
// Old: 8 dword lanes + float4 lane per edge ~= 10 addr/edge (~13us TA floor).
// New: one lane reads the whole 48B packed row as 3x float4 = 3 addr/edge.
// Only 9 values to reduce (6 feats + 3 sums) over 16 lanes.
__global__ void __launch_bounds__(256) k_agg3(const float* __restrict__ feat3p,
                                              const float* __restrict__ er3,
                                              const float* __restrict__ b3,
                                              const int* __restrict__ rowp,
                                              const int* __restrict__ col,
                                              float* __restrict__ out) {
    const int tid = threadIdx.x;
    const int wv = tid >> 6;
    const int lane = tid & 63;
    const int q = lane >> 4;
    const int ql = lane & 15;
    const int n = (blockIdx.x * 4 + wv) * 4 + q;   // grid exact: 3125*16 = 50000
    const int jb = rowp[n], je = rowp[n + 1];
    const float4 er4 = *reinterpret_cast<const float4*>(er3 + (size_t)n * 4);

    float acc[6];
#pragma unroll
    for (int j = 0; j < 6; ++j) acc[j] = 0.f;
    float sw0 = 0.f, sw1 = 0.f, sw2 = 0.f;

    for (int e = jb + ql; e < je; e += 16) {
        const int s = col[e];
        const float* __restrict__ row = feat3p + (size_t)s * 12;
        const float4 fa = *reinterpret_cast<const float4*>(row);      // el3[0..2], feat0
        const float4 fb = *reinterpret_cast<const float4*>(row + 4);  // feat1..feat4
        const float4 fc = *reinterpret_cast<const float4*>(row + 8);  // feat5, pad
        const float w0 = __expf(lrelu(fa.x + er4.x));
        const float w1 = __expf(lrelu(fa.y + er4.y));
        const float w2 = __expf(lrelu(fa.z + er4.z));
        sw0 += w0; sw1 += w1; sw2 += w2;
        acc[0] += w0 * fa.w;   // (h0,c0)
        acc[1] += w0 * fb.x;   // (h0,c1)
        acc[2] += w1 * fb.y;   // (h1,c0)
        acc[3] += w1 * fb.z;   // (h1,c1)
        acc[4] += w2 * fb.w;   // (h2,c0)
        acc[5] += w2 * fc.x;   // (h2,c1)
    }
#pragma unroll
    for (int off = 1; off < 16; off <<= 1) {
        sw0 += __shfl_xor(sw0, off);
        sw1 += __shfl_xor(sw1, off);
        sw2 += __shfl_xor(sw2, off);
#pragma unroll
        for (int j = 0; j < 6; ++j) acc[j] += __shfl_xor(acc[j], off);
    }
    if (ql == 0) {
        const bool has = (je > jb);
        const float i0 = has ? 1.f / sw0 : 0.f;
        const float i1 = has ? 1.f / sw1 : 0.f;
        const float i2 = has ? 1.f / sw2 : 0.f;
        const float o0 = acc[0] * i0 + acc[2] * i1 + acc[4] * i2 + b3[0] + b3[2] + b3[4];
        const float o1 = acc[1] * i0 + acc[3] * i1 + acc[5] * i2 + b3[1] + b3[3] + b3[5];
        *reinterpret_cast<float2*>(out + (size_t)n * 2) = make_float2(o0, o1);
    }
}

extern "C" void kernel_launch(void* const* d_in, const int* in_sizes, int n_in,
                              void* d_out, int out_size, void* d_ws, size_t ws_size,
                              hipStream_t stream) {
    const float* feats = (const float*)d_in[0];
    const int* src = (const int*)d_in[1];
    const int* dst = (const int*)d_in[2];
    const float* W1 = (const float*)d_in[3];
    const float* al1 = (const float*)d_in[4];
    const float* ar1 = (const float*)d_in[5];
    const float* b1 = (const float*)d_in[6];
    const float* W2 = (const float*)d_in[7];
    const float* al2 = (const float*)d_in[8];
    const float* ar2 = (const float*)d_in[9];
    const float* b2 = (const float*)d_in[10];
    const float* W3 = (const float*)d_in[11];
    const float* al3 = (const float*)d_in[12];
    const float* ar3 = (const float*)d_in[13];
    const float* b3 = (const float*)d_in[14];
    float* out = (float*)d_out;

    char* ws = (char*)d_ws;
    size_t off = 0;
    auto alloc = [&](size_t bytes) {
        void* p = ws + off;
        off += (bytes + 255) & ~(size_t)255;
        return p;
    };
    float* agg = (float*)alloc((size_t)N_NODES * 28 * 4);        // L1 agg fp32 [N][28]
    __half* aggH = (__half*)alloc((size_t)N_NODES * 192 * 2);    // L2 agg fp16 [N][192]
    __half* hbufH = (__half*)alloc((size_t)N_NODES * 64 * 2);    // fp16 hidden
    float* xp = (float*)alloc((size_t)N_NODES * 12 * 4);         // packed x+el1
    float* el = (float*)alloc((size_t)N_NODES * 4 * 4);
    float* er = (float*)alloc((size_t)N_NODES * 4 * 4);
    int* bcnt = (int*)alloc(512 * 4);                            // bcnt[256] + bfill[256]
    int* bfill = bcnt + 256;
    int* rowp = (int*)alloc((size_t)(N_NODES + 1) * 4);
    int* col = (int*)alloc((size_t)N_EDGES * 4);
    unsigned int* stage = (unsigned int*)alloc((size_t)N_EDGES * 4);
    __half* Wt16 = (__half*)alloc((size_t)64 * 192 * 2);         // 24 KB fp16 W2^T
    float* Wa2 = (float*)alloc(256 * 4);
    float* Wr2 = (float*)alloc(256 * 4);
    float* feat3p = (float*)alloc((size_t)N_NODES * 12 * 4);     // packed el3+feat3
    (void)ws_size;

    const int ab = N_NODES / 4;             // wave/node kernels: 4 waves/block
    const int qb = N_NODES / 16;            // quarter-wave/node kernels: 16 nodes/block
    const int gb2 = N_NODES / 16;           // k_gemm2: 16 nodes/block
    const int gbm = (N_NODES + 63) / 64;    // k_gemm3m: 64 nodes/block
    const int nb3 = (N_NODES + 31) / 32;

    // ---- fused front (cntb | el9p | prepW | prepA) + CSR build ----
    hipMemsetAsync(bcnt, 0, 512 * 4, stream);
    k_front<<<NB_BIN + NB_EL + NB_PW + 1, 256, 0, stream>>>(
        dst, bcnt, feats, W1, al1, ar1, xp, er, W2, Wt16, al2, ar2, Wa2, Wr2);
    k_bin<<<NB_BIN, 256, 0, stream>>>(src, dst, bcnt, bfill, stage);
    k_bscatter2<<<NBKT, 256, 0, stream>>>(stage, bcnt, rowp, col);

    // ---- layer 1 ----
    k_aggw9<<<qb, 256, 0, stream>>>(xp, er, rowp, col, agg);
    k_gemm2<9, 28, 9><<<gb2, 192, 0, stream>>>(agg, W1, b1, Wa2, Wr2, hbufH, el, er);

    // ---- layer 2 ----
    k_aggw64<<<ab, 256, 0, stream>>>(hbufH, el, er, rowp, col, aggH);
    k_gemm3m<<<gbm, 256, 0, stream>>>(aggH, Wt16, b2, hbufH);

    // ---- layer 3 ----
    k_feat3<<<nb3, 256, 0, stream>>>(hbufH, W3, al3, ar3, feat3p, er);
    k_agg3<<<qb, 256, 0, stream>>>(feat3p, er, b3, rowp, col, out);
}

// Round 3
// 239.744 us; speedup vs baseline: 1.1346x; 1.0936x over previous
//
#include <hip/hip_runtime.h>
#include <hip/hip_fp16.h>

#define N_NODES 50000
#define N_EDGES 800000
#define NBKT 196            // ceil(50000 / 256) coarse buckets (dst >> 8)
#define EPB_BIN 4096        // edges per binning block
#define NB_BIN ((N_EDGES + EPB_BIN - 1) / EPB_BIN)   // 196
#define NB_EL 196           // ceil(50000/256) blocks for el9p role
#define NB_PW 48            // 64*192/256 blocks for prepW role

typedef _Float16 half8 __attribute__((ext_vector_type(8)));
typedef float f32x4 __attribute__((ext_vector_type(4)));

static __device__ __forceinline__ float lrelu(float x) { return fmaxf(x, 0.2f * x); }

// ---------------- fused front kernel: cntb | el9p | prepW | prepA -----------
__global__ void __launch_bounds__(256) k_front(const int* __restrict__ dst,
                                               int* __restrict__ bcnt,
                                               const float* __restrict__ x,
                                               const float* __restrict__ W1,
                                               const float* __restrict__ al1,
                                               const float* __restrict__ ar1,
                                               float* __restrict__ xp,
                                               float* __restrict__ er,
                                               const float* __restrict__ W2,
                                               __half* __restrict__ Wt16,
                                               const float* __restrict__ al2,
                                               const float* __restrict__ ar2,
                                               float* __restrict__ Wa2,
                                               float* __restrict__ Wr2) {
    __shared__ int lcnt[NBKT];
    __shared__ float sWa[9 * 3];
    __shared__ float sWr[9 * 3];
    const int t = threadIdx.x;
    const int b = blockIdx.x;

    if (b < NB_BIN) {
        const int e0 = b * EPB_BIN;
        for (int i = t; i < NBKT; i += 256) lcnt[i] = 0;
        __syncthreads();
#pragma unroll
        for (int i = 0; i < 16; ++i) {
            const int e = e0 + i * 256 + t;
            if (e < N_EDGES) atomicAdd(&lcnt[dst[e] >> 8], 1);
        }
        __syncthreads();
        for (int i = t; i < NBKT; i += 256)
            if (lcnt[i]) atomicAdd(&bcnt[i], lcnt[i]);
        return;
    }
    if (b < NB_BIN + NB_EL) {
        if (t < 27) {
            const int h = t / 9, k = t % 9;
            float sa = 0.f, sr = 0.f;
            for (int f = 0; f < 64; ++f) {
                const float w = W1[k * 192 + h * 64 + f];
                sa += w * al1[h * 64 + f];
                sr += w * ar1[h * 64 + f];
            }
            sWa[k * 3 + h] = sa;
            sWr[k * 3 + h] = sr;
        }
        __syncthreads();
        const int n = (b - NB_BIN) * 256 + t;
        if (n >= N_NODES) return;
        const float* __restrict__ xr = x + (size_t)n * 9;
        float xv[9];
        float a0 = 0.f, a1 = 0.f, a2 = 0.f, r0 = 0.f, r1 = 0.f, r2 = 0.f;
#pragma unroll
        for (int k = 0; k < 9; ++k) {
            xv[k] = xr[k];
            a0 += xv[k] * sWa[k * 3 + 0];
            a1 += xv[k] * sWa[k * 3 + 1];
            a2 += xv[k] * sWa[k * 3 + 2];
            r0 += xv[k] * sWr[k * 3 + 0];
            r1 += xv[k] * sWr[k * 3 + 1];
            r2 += xv[k] * sWr[k * 3 + 2];
        }
        float* __restrict__ xo = xp + (size_t)n * 12;
        *reinterpret_cast<float4*>(xo) = make_float4(xv[0], xv[1], xv[2], xv[3]);
        *reinterpret_cast<float4*>(xo + 4) = make_float4(xv[4], xv[5], xv[6], xv[7]);
        *reinterpret_cast<float4*>(xo + 8) = make_float4(xv[8], a0, a1, a2);
        *reinterpret_cast<float4*>(er + (size_t)n * 4) = make_float4(r0, r1, r2, 0.f);
        return;
    }
    if (b < NB_BIN + NB_EL + NB_PW) {
        const int idx = (b - (NB_BIN + NB_EL)) * 256 + t;
        if (idx < 64 * 192) {
            const int n = idx / 192, ke = idx % 192;
            Wt16[idx] = __float2half(W2[(ke & 63) * 192 + (ke >> 6) * 64 + n]);
        }
        return;
    }
    if (t < 192) {
        const int h = t >> 6, k = t & 63;
        float sa = 0.f, sr = 0.f;
        for (int f = 0; f < 64; ++f) {
            const float w = W2[k * 192 + h * 64 + f];
            sa += w * al2[h * 64 + f];
            sr += w * ar2[h * 64 + f];
        }
        Wa2[k * 4 + h] = sa;
        Wr2[k * 4 + h] = sr;
        if (h == 0) { Wa2[k * 4 + 3] = 0.f; Wr2[k * 4 + 3] = 0.f; }
    }
}

// ---------------- bin edges (bucket scan inlined) ----------------------------
__global__ void __launch_bounds__(256) k_bin(const int* __restrict__ src,
                                             const int* __restrict__ dst,
                                             const int* __restrict__ bcnt,
                                             int* __restrict__ bfill,
                                             unsigned int* __restrict__ stage) {
    __shared__ int lcnt[NBKT];
    __shared__ int gb[NBKT];
    __shared__ int lf[NBKT];
    __shared__ int sscan[256];
    __shared__ int sbase[256];
    const int t = threadIdx.x;
    const int e0 = blockIdx.x * EPB_BIN;
    const int bv = (t < NBKT) ? bcnt[t] : 0;
    sscan[t] = bv;
    if (t < NBKT) lcnt[t] = 0;
    __syncthreads();
    for (int off = 1; off < 256; off <<= 1) {
        const int u = (t >= off) ? sscan[t - off] : 0;
        __syncthreads();
        sscan[t] += u;
        __syncthreads();
    }
    sbase[t] = sscan[t] - bv;
    int dcache[16];
#pragma unroll
    for (int i = 0; i < 16; ++i) {
        const int e = e0 + i * 256 + t;
        if (e < N_EDGES) {
            const int d = dst[e];
            dcache[i] = d;
            atomicAdd(&lcnt[d >> 8], 1);
        } else dcache[i] = -1;
    }
    __syncthreads();
    for (int i = t; i < NBKT; i += 256) {
        gb[i] = sbase[i] + atomicAdd(&bfill[i], lcnt[i]);
        lf[i] = 0;
    }
    __syncthreads();
#pragma unroll
    for (int i = 0; i < 16; ++i) {
        const int e = e0 + i * 256 + t;
        if (e < N_EDGES) {
            const int d = dcache[i];
            const int bk = d >> 8;
            const int r = atomicAdd(&lf[bk], 1);
            stage[gb[bk] + r] = (unsigned int)src[e] | ((unsigned int)(d & 255) << 16);
        }
    }
}

// ---------------- per bucket scatter (bucket scan inlined) ------------------
__global__ void __launch_bounds__(256) k_bscatter2(const unsigned int* __restrict__ stage,
                                                   const int* __restrict__ bcnt,
                                                   int* __restrict__ rowp,
                                                   int* __restrict__ col) {
    __shared__ int lcnt[256];
    __shared__ int lpos[256];
    __shared__ int sexc[256];
    __shared__ int sscan[256];
    const int t = threadIdx.x;
    const int b = blockIdx.x;
    const int n0 = b << 8;
    const int bv = (t < NBKT) ? bcnt[t] : 0;
    sscan[t] = bv;
    lcnt[t] = 0;
    __syncthreads();
    for (int off = 1; off < 256; off <<= 1) {
        const int u = (t >= off) ? sscan[t - off] : 0;
        __syncthreads();
        sscan[t] += u;
        __syncthreads();
    }
    const int base = (b == 0) ? 0 : sscan[b - 1];
    const int end = sscan[b];

    for (int j = base + t; j < end; j += 256)
        atomicAdd(&lcnt[(stage[j] >> 16) & 255], 1);
    __syncthreads();
    const int v = lcnt[t];
    lpos[t] = v;
    __syncthreads();
    for (int off = 1; off < 256; off <<= 1) {
        const int u = (t >= off) ? lpos[t - off] : 0;
        __syncthreads();
        lpos[t] += u;
        __syncthreads();
    }
    sexc[t] = lpos[t] - v;
    if (n0 + t < N_NODES) rowp[n0 + t] = base + sexc[t];
    if (b == NBKT - 1 && t == 0) rowp[N_NODES] = N_EDGES;
    lcnt[t] = 0;   // reuse as fill counters
    __syncthreads();
    for (int j = base + t; j < end; j += 256) {
        const unsigned int e = stage[j];
        const int local = (int)(e >> 16) & 255;
        const int r = atomicAdd(&lcnt[local], 1);
        col[base + sexc[local] + r] = (int)(e & 0xFFFFu);
    }
}

// ---------------- fused L1: aggw9 + gemm2 (LDS handoff, no agg buffer) -------
// Both halves operate on the same 16 nodes per block; the [16][28] aggregate
// never touches global memory. Saves 11.2 MB HBM round-trip + 1 dispatch.
__global__ void __launch_bounds__(256) k_l1(const float* __restrict__ xp,
                                            const float* __restrict__ er_in,
                                            const int* __restrict__ rowp,
                                            const int* __restrict__ col,
                                            const float* __restrict__ W1,
                                            const float* __restrict__ b1,
                                            const float* __restrict__ Wa2,
                                            const float* __restrict__ Wr2,
                                            __half* __restrict__ hout,
                                            float* __restrict__ el,
                                            float* __restrict__ er_out) {
    __shared__ float At[16 * 28];
    __shared__ float part[3][16][64];
    const int t = threadIdx.x;
    const int wv = t >> 6;
    const int lane = t & 63;
    const int q = lane >> 4;            // node slot within wave
    const int ql = lane & 15;           // lane within quarter
    const int li = wv * 4 + q;          // local node 0..15
    const int nbase = blockIdx.x * 16;  // 3125 * 16 = 50000 exact
    const int n = nbase + li;

    // ---- aggregation (lane-per-edge, quarter-wave per node) ----
    {
        const int jb = rowp[n], je = rowp[n + 1];
        const float4 er4 = *reinterpret_cast<const float4*>(er_in + (size_t)n * 4);
        float acc[27];
#pragma unroll
        for (int j = 0; j < 27; ++j) acc[j] = 0.f;
        float sw0 = 0.f, sw1 = 0.f, sw2 = 0.f;

        for (int e = jb + ql; e < je; e += 16) {
            const int s = col[e];
            const float* __restrict__ row = xp + (size_t)s * 12;
            const float4 xa = *reinterpret_cast<const float4*>(row);
            const float4 xb = *reinterpret_cast<const float4*>(row + 4);
            const float4 xc = *reinterpret_cast<const float4*>(row + 8);
            const float w0 = __expf(lrelu(xc.y + er4.x));
            const float w1 = __expf(lrelu(xc.z + er4.y));
            const float w2 = __expf(lrelu(xc.w + er4.z));
            sw0 += w0; sw1 += w1; sw2 += w2;
            const float xv[9] = {xa.x, xa.y, xa.z, xa.w, xb.x, xb.y, xb.z, xb.w, xc.x};
#pragma unroll
            for (int k = 0; k < 9; ++k) {
                acc[0 + k]  += w0 * xv[k];
                acc[9 + k]  += w1 * xv[k];
                acc[18 + k] += w2 * xv[k];
            }
        }
#pragma unroll
        for (int off = 1; off < 16; off <<= 1) {
            sw0 += __shfl_xor(sw0, off);
            sw1 += __shfl_xor(sw1, off);
            sw2 += __shfl_xor(sw2, off);
#pragma unroll
            for (int j = 0; j < 27; ++j) acc[j] += __shfl_xor(acc[j], off);
        }
        if (ql == 0) {
            const bool has = (je > jb);
            const float i0 = has ? 1.f / sw0 : 0.f;
            const float i1 = has ? 1.f / sw1 : 0.f;
            const float i2 = has ? 1.f / sw2 : 0.f;
            float* __restrict__ ao = At + li * 28;
#pragma unroll
            for (int k = 0; k < 9; ++k) {
                ao[k] = acc[k] * i0;
                ao[9 + k] = acc[9 + k] * i1;
                ao[18 + k] = acc[18 + k] * i2;
            }
        }
    }
    __syncthreads();

    // ---- GEMM (h = wave id, c = lane) + fused el2/er2 epilogue ----
    {
        const int h = wv;               // 0..3; h==3 idle for partials
        const int c = lane;
        if (h < 3) {
            float wreg[9];
#pragma unroll
            for (int k = 0; k < 9; ++k) wreg[k] = W1[k * 192 + h * 64 + c];
#pragma unroll
            for (int i = 0; i < 16; ++i) {
                const float* __restrict__ arp = At + i * 28 + h * 9;
                float acc = 0.f;
#pragma unroll
                for (int k = 0; k < 9; ++k) acc += arp[k] * wreg[k];
                part[h][i][c] = acc;
            }
        }
        __syncthreads();
        const float4 wa = *reinterpret_cast<const float4*>(Wa2 + c * 4);
        const float4 wr = *reinterpret_cast<const float4*>(Wr2 + c * 4);
        const float bsum = b1[c] + b1[64 + c] + b1[128 + c];
        for (int idx = t; idx < 1024; idx += 256) {
            const int i = idx >> 6, cc = idx & 63;  // cc == c (stride 256)
            const float v = part[0][i][cc] + part[1][i][cc] + part[2][i][cc] + bsum;
            hout[(size_t)(nbase + i) * 64 + cc] = __float2half(v);
            float e0 = v * wa.x, e1 = v * wa.y, e2 = v * wa.z;
            float r0 = v * wr.x, r1 = v * wr.y, r2 = v * wr.z;
#pragma unroll
            for (int off = 32; off > 0; off >>= 1) {
                e0 += __shfl_xor(e0, off); e1 += __shfl_xor(e1, off); e2 += __shfl_xor(e2, off);
                r0 += __shfl_xor(r0, off); r1 += __shfl_xor(r1, off); r2 += __shfl_xor(r2, off);
            }
            if (cc == 0) {
                *reinterpret_cast<float4*>(el + (size_t)(nbase + i) * 4) = make_float4(e0, e1, e2, 0.f);
                *reinterpret_cast<float4*>(er_out + (size_t)(nbase + i) * 4) = make_float4(r0, r1, r2, 0.f);
            }
        }
    }
}

// ---------------- L2 aggregation v1 (verbatim round-0; measured 41.5us) ------
// Divergent-gather floor: ~1 dword/cy/CU -> 32 dwords/edge = ~41.7us. v1 is at it.
__global__ void __launch_bounds__(256) k_aggw64(const __half* __restrict__ x,
                                                const float* __restrict__ el,
                                                const float* __restrict__ er,
                                                const int* __restrict__ rowp,
                                                const int* __restrict__ col,
                                                __half* __restrict__ agg) {
    const int wv = threadIdx.x >> 6;
    const int lane = threadIdx.x & 63;
    const int n = blockIdx.x * 4 + wv;          // grid exact
    const int jb = rowp[n], je = rowp[n + 1];

    __shared__ float wbuf[4][3][68];
    __shared__ int cbuf[4][68];
    const float4 er4 = *reinterpret_cast<const float4*>(er + (size_t)n * 4);
    const int p = lane >> 5;
    const int f0 = (lane & 31) * 2;
    float a00 = 0.f, a01 = 0.f, a02 = 0.f;
    float a10 = 0.f, a11 = 0.f, a12 = 0.f;
    float sw0 = 0.f, sw1 = 0.f, sw2 = 0.f;

    for (int c0 = jb; c0 < je; c0 += 64) {
        const int cnt = min(64, je - c0);
        float w0 = 0.f, w1 = 0.f, w2 = 0.f;
        if (lane < cnt) {
            const int s = col[c0 + lane];
            cbuf[wv][lane] = s;
            const float4 e4 = *reinterpret_cast<const float4*>(el + (size_t)s * 4);
            w0 = __expf(lrelu(e4.x + er4.x));
            w1 = __expf(lrelu(e4.y + er4.y));
            w2 = __expf(lrelu(e4.z + er4.z));
            wbuf[wv][0][lane] = w0;
            wbuf[wv][1][lane] = w1;
            wbuf[wv][2][lane] = w2;
        }
        sw0 += w0; sw1 += w1; sw2 += w2;
        int e = 0;
        for (; e + 2 <= cnt; e += 2) {
            const int ei = e + p;
            const int s = cbuf[wv][ei];
            const float2 xv = __half22float2(
                *reinterpret_cast<const __half2*>(x + (size_t)s * 64 + f0));
            const float we0 = wbuf[wv][0][ei];
            const float we1 = wbuf[wv][1][ei];
            const float we2 = wbuf[wv][2][ei];
            a00 += we0 * xv.x; a01 += we1 * xv.x; a02 += we2 * xv.x;
            a10 += we0 * xv.y; a11 += we1 * xv.y; a12 += we2 * xv.y;
        }
        if (e < cnt && p == 0) {
            const int s = cbuf[wv][e];
            const float2 xv = __half22float2(
                *reinterpret_cast<const __half2*>(x + (size_t)s * 64 + f0));
            const float we0 = wbuf[wv][0][e];
            const float we1 = wbuf[wv][1][e];
            const float we2 = wbuf[wv][2][e];
            a00 += we0 * xv.x; a01 += we1 * xv.x; a02 += we2 * xv.x;
            a10 += we0 * xv.y; a11 += we1 * xv.y; a12 += we2 * xv.y;
        }
    }
    a00 += __shfl_xor(a00, 32); a01 += __shfl_xor(a01, 32); a02 += __shfl_xor(a02, 32);
    a10 += __shfl_xor(a10, 32); a11 += __shfl_xor(a11, 32); a12 += __shfl_xor(a12, 32);
#pragma unroll
    for (int off = 32; off > 0; off >>= 1) {
        sw0 += __shfl_xor(sw0, off);
        sw1 += __shfl_xor(sw1, off);
        sw2 += __shfl_xor(sw2, off);
    }
    if (lane < 32) {
        __half* __restrict__ ao = agg + (size_t)n * 192;
        if (je > jb) {
            const float i0 = 1.f / sw0, i1 = 1.f / sw1, i2 = 1.f / sw2;
            *reinterpret_cast<__half2*>(ao + f0) = __floats2half2_rn(a00 * i0, a10 * i0);
            *reinterpret_cast<__half2*>(ao + 64 + f0) = __floats2half2_rn(a01 * i1, a11 * i1);
            *reinterpret_cast<__half2*>(ao + 128 + f0) = __floats2half2_rn(a02 * i2, a12 * i2);
        } else {
            const __half2 z = __floats2half2_rn(0.f, 0.f);
            *reinterpret_cast<__half2*>(ao + f0) = z;
            *reinterpret_cast<__half2*>(ao + 64 + f0) = z;
            *reinterpret_cast<__half2*>(ao + 128 + f0) = z;
        }
    }
}

// ---------------- fused L2 GEMM (MFMA) + layer-3 features (LDS handoff) ------
// gemm3m's 64 hidden rows per block are exactly what feat3 consumes; keep them
// in LDS, never write the L2 hidden state to global. Saves 12.8 MB + 1 dispatch.
__global__ void __launch_bounds__(256) k_l23(const __half* __restrict__ aggH,
                                             const __half* __restrict__ Wt,
                                             const float* __restrict__ b2,
                                             const float* __restrict__ W3,
                                             const float* __restrict__ al3,
                                             const float* __restrict__ ar3,
                                             float* __restrict__ feat3p,
                                             float* __restrict__ er3) {
    __shared__ float xl[64 * 68];
    __shared__ float Wl[64 * 6];
    __shared__ float Wal[64 * 3];
    __shared__ float Wrl[64 * 3];
    const int t = threadIdx.x;
    const int n0 = blockIdx.x * 64;             // 782 blocks; last has nvalid=16
    const int nvalid = min(64, N_NODES - n0);

    // ---- MFMA GEMM: hidden = aggH @ W2^T + b2sum, straight into LDS ----
    {
        const int wv = t >> 6;
        const int lane = t & 63;
        const int quad = lane >> 4;
        const int t16 = lane & 15;
        const int nwave = n0 + wv * 16;
        const int arow = min(nwave + t16, N_NODES - 1);
        half8 a[6];
#pragma unroll
        for (int kb = 0; kb < 6; ++kb)
            a[kb] = *reinterpret_cast<const half8*>(aggH + (size_t)arow * 192 + kb * 32 + quad * 8);
#pragma unroll
        for (int nt = 0; nt < 4; ++nt) {
            const int c = nt * 16 + t16;
            const float bs = b2[c] + b2[64 + c] + b2[128 + c];
            const __half* __restrict__ bt = Wt + (size_t)c * 192 + quad * 8;
            f32x4 acc = {0.f, 0.f, 0.f, 0.f};
#pragma unroll
            for (int kb = 0; kb < 6; ++kb) {
                const half8 bfr = *reinterpret_cast<const half8*>(bt + kb * 32);
                acc = __builtin_amdgcn_mfma_f32_16x16x32_f16(a[kb], bfr, acc, 0, 0, 0);
            }
#pragma unroll
            for (int r = 0; r < 4; ++r)
                xl[(wv * 16 + quad * 4 + r) * 68 + c] = acc[r] + bs;
        }
    }
    // ---- weight prep (concurrent with xl writes; disjoint LDS) ----
    for (int idx = t; idx < 384; idx += 256) Wl[idx] = W3[idx];
    if (t < 192) {
        const int k = t & 63, h = t >> 6;
        Wal[k * 3 + h] = W3[k * 6 + h * 2] * al3[h * 2] + W3[k * 6 + h * 2 + 1] * al3[h * 2 + 1];
        Wrl[k * 3 + h] = W3[k * 6 + h * 2] * ar3[h * 2] + W3[k * 6 + h * 2 + 1] * ar3[h * 2 + 1];
    }
    __syncthreads();

    // ---- layer-3 packed features, two 32-row passes ----
#pragma unroll
    for (int hp = 0; hp < 2; ++hp) {
        const int i = (t >> 3) + hp * 32;
        const int slot = t & 7;
        if (i < nvalid && slot < 6) {
            float acc = 0.f;
#pragma unroll
            for (int k4 = 0; k4 < 16; ++k4) {
                const float4 xv = *reinterpret_cast<const float4*>(&xl[i * 68 + 4 * k4]);
                acc += Wl[(4 * k4 + 0) * 6 + slot] * xv.x;
                acc += Wl[(4 * k4 + 1) * 6 + slot] * xv.y;
                acc += Wl[(4 * k4 + 2) * 6 + slot] * xv.z;
                acc += Wl[(4 * k4 + 3) * 6 + slot] * xv.w;
            }
            feat3p[(size_t)(n0 + i) * 12 + 3 + slot] = acc;   // feat at offsets 3..8
        }
        if (t < 192) {
            const int ii = t / 6 + hp * 32, ss = t % 6;
            if (ii < nvalid) {
                const int hh = (ss < 3) ? ss : ss - 3;
                const float* __restrict__ wt = (ss < 3) ? Wal : Wrl;
                float acc = 0.f;
#pragma unroll 4
                for (int k = 0; k < 64; ++k) acc += xl[ii * 68 + k] * wt[k * 3 + hh];
                if (ss < 3) feat3p[(size_t)(n0 + ii) * 12 + hh] = acc;   // el3 at 0..2
                else        er3[(size_t)(n0 + ii) * 4 + hh] = acc;
            }
        }
    }
}

// ---------------- layer-3 aggregation: lane-per-edge (verbatim round-1) ------
__global__ void __launch_bounds__(256) k_agg3(const float* __restrict__ feat3p,
                                              const float* __restrict__ er3,
                                              const float* __restrict__ b3,
                                              const int* __restrict__ rowp,
                                              const int* __restrict__ col,
                                              float* __restrict__ out) {
    const int tid = threadIdx.x;
    const int wv = tid >> 6;
    const int lane = tid & 63;
    const int q = lane >> 4;
    const int ql = lane & 15;
    const int n = (blockIdx.x * 4 + wv) * 4 + q;   // grid exact: 3125*16 = 50000
    const int jb = rowp[n], je = rowp[n + 1];
    const float4 er4 = *reinterpret_cast<const float4*>(er3 + (size_t)n * 4);

    float acc[6];
#pragma unroll
    for (int j = 0; j < 6; ++j) acc[j] = 0.f;
    float sw0 = 0.f, sw1 = 0.f, sw2 = 0.f;

    for (int e = jb + ql; e < je; e += 16) {
        const int s = col[e];
        const float* __restrict__ row = feat3p + (size_t)s * 12;
        const float4 fa = *reinterpret_cast<const float4*>(row);      // el3[0..2], feat0
        const float4 fb = *reinterpret_cast<const float4*>(row + 4);  // feat1..feat4
        const float4 fc = *reinterpret_cast<const float4*>(row + 8);  // feat5, pad
        const float w0 = __expf(lrelu(fa.x + er4.x));
        const float w1 = __expf(lrelu(fa.y + er4.y));
        const float w2 = __expf(lrelu(fa.z + er4.z));
        sw0 += w0; sw1 += w1; sw2 += w2;
        acc[0] += w0 * fa.w;
        acc[1] += w0 * fb.x;
        acc[2] += w1 * fb.y;
        acc[3] += w1 * fb.z;
        acc[4] += w2 * fb.w;
        acc[5] += w2 * fc.x;
    }
#pragma unroll
    for (int off = 1; off < 16; off <<= 1) {
        sw0 += __shfl_xor(sw0, off);
        sw1 += __shfl_xor(sw1, off);
        sw2 += __shfl_xor(sw2, off);
#pragma unroll
        for (int j = 0; j < 6; ++j) acc[j] += __shfl_xor(acc[j], off);
    }
    if (ql == 0) {
        const bool has = (je > jb);
        const float i0 = has ? 1.f / sw0 : 0.f;
        const float i1 = has ? 1.f / sw1 : 0.f;
        const float i2 = has ? 1.f / sw2 : 0.f;
        const float o0 = acc[0] * i0 + acc[2] * i1 + acc[4] * i2 + b3[0] + b3[2] + b3[4];
        const float o1 = acc[1] * i0 + acc[3] * i1 + acc[5] * i2 + b3[1] + b3[3] + b3[5];
        *reinterpret_cast<float2*>(out + (size_t)n * 2) = make_float2(o0, o1);
    }
}

extern "C" void kernel_launch(void* const* d_in, const int* in_sizes, int n_in,
                              void* d_out, int out_size, void* d_ws, size_t ws_size,
                              hipStream_t stream) {
    const float* feats = (const float*)d_in[0];
    const int* src = (const int*)d_in[1];
    const int* dst = (const int*)d_in[2];
    const float* W1 = (const float*)d_in[3];
    const float* al1 = (const float*)d_in[4];
    const float* ar1 = (const float*)d_in[5];
    const float* b1 = (const float*)d_in[6];
    const float* W2 = (const float*)d_in[7];
    const float* al2 = (const float*)d_in[8];
    const float* ar2 = (const float*)d_in[9];
    const float* b2 = (const float*)d_in[10];
    const float* W3 = (const float*)d_in[11];
    const float* al3 = (const float*)d_in[12];
    const float* ar3 = (const float*)d_in[13];
    const float* b3 = (const float*)d_in[14];
    float* out = (float*)d_out;

    char* ws = (char*)d_ws;
    size_t off = 0;
    auto alloc = [&](size_t bytes) {
        void* p = ws + off;
        off += (bytes + 255) & ~(size_t)255;
        return p;
    };
    __half* aggH = (__half*)alloc((size_t)N_NODES * 192 * 2);    // L2 agg fp16 [N][192]
    __half* hbufH = (__half*)alloc((size_t)N_NODES * 64 * 2);    // fp16 L1 hidden
    float* xp = (float*)alloc((size_t)N_NODES * 12 * 4);         // packed x+el1
    float* el = (float*)alloc((size_t)N_NODES * 4 * 4);
    float* er = (float*)alloc((size_t)N_NODES * 4 * 4);
    int* bcnt = (int*)alloc(512 * 4);                            // bcnt[256] + bfill[256]
    int* bfill = bcnt + 256;
    int* rowp = (int*)alloc((size_t)(N_NODES + 1) * 4);
    int* col = (int*)alloc((size_t)N_EDGES * 4);
    unsigned int* stage = (unsigned int*)alloc((size_t)N_EDGES * 4);
    __half* Wt16 = (__half*)alloc((size_t)64 * 192 * 2);         // 24 KB fp16 W2^T
    float* Wa2 = (float*)alloc(256 * 4);
    float* Wr2 = (float*)alloc(256 * 4);
    float* feat3p = (float*)alloc((size_t)N_NODES * 12 * 4);     // packed el3+feat3
    (void)ws_size;

    const int ab = N_NODES / 4;             // k_aggw64: 4 waves/block
    const int qb = N_NODES / 16;            // 16 nodes/block kernels
    const int lb = (N_NODES + 63) / 64;     // k_l23: 64 nodes/block

    // ---- CSR build + front prep ----
    hipMemsetAsync(bcnt, 0, 512 * 4, stream);
    k_front<<<NB_BIN + NB_EL + NB_PW + 1, 256, 0, stream>>>(
        dst, bcnt, feats, W1, al1, ar1, xp, er, W2, Wt16, al2, ar2, Wa2, Wr2);
    k_bin<<<NB_BIN, 256, 0, stream>>>(src, dst, bcnt, bfill, stage);
    k_bscatter2<<<NBKT, 256, 0, stream>>>(stage, bcnt, rowp, col);

    // ---- layer 1 (agg + GEMM fused) ----
    k_l1<<<qb, 256, 0, stream>>>(xp, er, rowp, col, W1, b1, Wa2, Wr2, hbufH, el, er);

    // ---- layer 2 aggregation ----
    k_aggw64<<<ab, 256, 0, stream>>>(hbufH, el, er, rowp, col, aggH);

    // ---- layer-2 GEMM + layer-3 features (fused) ----
    k_l23<<<lb, 256, 0, stream>>>(aggH, Wt16, b2, W3, al3, ar3, feat3p, er);

    // ---- layer 3 aggregation ----
    k_agg3<<<qb, 256, 0, stream>>>(feat3p, er, b3, rowp, col, out);
}

// Round 4
// 225.057 us; speedup vs baseline: 1.2086x; 1.0653x over previous
//
#include <hip/hip_runtime.h>
#include <hip/hip_fp16.h>

#define N_NODES 50000
#define N_EDGES 800000
#define NBKT 196            // ceil(50000 / 256) coarse buckets (dst >> 8)
#define EPB_BIN 4096        // edges per binning block
#define NB_BIN ((N_EDGES + EPB_BIN - 1) / EPB_BIN)   // 196
#define NB_EL 196           // ceil(50000/256) blocks for el9p role
#define NB_PW 48            // 64*192/256 blocks for prepW role

typedef _Float16 half8 __attribute__((ext_vector_type(8)));
typedef float f32x4 __attribute__((ext_vector_type(4)));

static __device__ __forceinline__ float lrelu(float x) { return fmaxf(x, 0.2f * x); }

static __device__ __forceinline__ float2 h2f(float bits) {
    union { float f; __half2 h; } u;
    u.f = bits;
    return __half22float2(u.h);
}
static __device__ __forceinline__ float f2h2(float a, float b) {
    union { float f; __half2 h; } u;
    u.h = __floats2half2_rn(a, b);
    return u.f;
}

// ---------------- fused front kernel: cntb | el9p | prepW | prepA -----------
// el9p now writes xph[N][8 floats = 32B]: {el0,el1,el2 (f32), x0..x8 (f16), pad}
__global__ void __launch_bounds__(256) k_front(const int* __restrict__ dst,
                                               int* __restrict__ bcnt,
                                               const float* __restrict__ x,
                                               const float* __restrict__ W1,
                                               const float* __restrict__ al1,
                                               const float* __restrict__ ar1,
                                               float* __restrict__ xph,
                                               float* __restrict__ er,
                                               const float* __restrict__ W2,
                                               __half* __restrict__ Wt16,
                                               const float* __restrict__ al2,
                                               const float* __restrict__ ar2,
                                               float* __restrict__ Wa2,
                                               float* __restrict__ Wr2) {
    __shared__ int lcnt[NBKT];
    __shared__ float sWa[9 * 3];
    __shared__ float sWr[9 * 3];
    const int t = threadIdx.x;
    const int b = blockIdx.x;

    if (b < NB_BIN) {
        const int e0 = b * EPB_BIN;
        for (int i = t; i < NBKT; i += 256) lcnt[i] = 0;
        __syncthreads();
#pragma unroll
        for (int i = 0; i < 16; ++i) {
            const int e = e0 + i * 256 + t;
            if (e < N_EDGES) atomicAdd(&lcnt[dst[e] >> 8], 1);
        }
        __syncthreads();
        for (int i = t; i < NBKT; i += 256)
            if (lcnt[i]) atomicAdd(&bcnt[i], lcnt[i]);
        return;
    }
    if (b < NB_BIN + NB_EL) {
        if (t < 27) {
            const int h = t / 9, k = t % 9;
            float sa = 0.f, sr = 0.f;
            for (int f = 0; f < 64; ++f) {
                const float w = W1[k * 192 + h * 64 + f];
                sa += w * al1[h * 64 + f];
                sr += w * ar1[h * 64 + f];
            }
            sWa[k * 3 + h] = sa;
            sWr[k * 3 + h] = sr;
        }
        __syncthreads();
        const int n = (b - NB_BIN) * 256 + t;
        if (n >= N_NODES) return;
        const float* __restrict__ xr = x + (size_t)n * 9;
        float xv[9];
        float a0 = 0.f, a1 = 0.f, a2 = 0.f, r0 = 0.f, r1 = 0.f, r2 = 0.f;
#pragma unroll
        for (int k = 0; k < 9; ++k) {
            xv[k] = xr[k];
            a0 += xv[k] * sWa[k * 3 + 0];
            a1 += xv[k] * sWa[k * 3 + 1];
            a2 += xv[k] * sWa[k * 3 + 2];
            r0 += xv[k] * sWr[k * 3 + 0];
            r1 += xv[k] * sWr[k * 3 + 1];
            r2 += xv[k] * sWr[k * 3 + 2];
        }
        float* __restrict__ xo = xph + (size_t)n * 8;
        *reinterpret_cast<float4*>(xo) = make_float4(a0, a1, a2, f2h2(xv[0], xv[1]));
        *reinterpret_cast<float4*>(xo + 4) =
            make_float4(f2h2(xv[2], xv[3]), f2h2(xv[4], xv[5]),
                        f2h2(xv[6], xv[7]), f2h2(xv[8], 0.f));
        *reinterpret_cast<float4*>(er + (size_t)n * 4) = make_float4(r0, r1, r2, 0.f);
        return;
    }
    if (b < NB_BIN + NB_EL + NB_PW) {
        const int idx = (b - (NB_BIN + NB_EL)) * 256 + t;
        if (idx < 64 * 192) {
            const int n = idx / 192, ke = idx % 192;
            Wt16[idx] = __float2half(W2[(ke & 63) * 192 + (ke >> 6) * 64 + n]);
        }
        return;
    }
    if (t < 192) {
        const int h = t >> 6, k = t & 63;
        float sa = 0.f, sr = 0.f;
        for (int f = 0; f < 64; ++f) {
            const float w = W2[k * 192 + h * 64 + f];
            sa += w * al2[h * 64 + f];
            sr += w * ar2[h * 64 + f];
        }
        Wa2[k * 4 + h] = sa;
        Wr2[k * 4 + h] = sr;
        if (h == 0) { Wa2[k * 4 + 3] = 0.f; Wr2[k * 4 + 3] = 0.f; }
    }
}

// ---------------- bin edges (bucket scan inlined) ----------------------------
__global__ void __launch_bounds__(256) k_bin(const int* __restrict__ src,
                                             const int* __restrict__ dst,
                                             const int* __restrict__ bcnt,
                                             int* __restrict__ bfill,
                                             unsigned int* __restrict__ stage) {
    __shared__ int lcnt[NBKT];
    __shared__ int gb[NBKT];
    __shared__ int lf[NBKT];
    __shared__ int sscan[256];
    __shared__ int sbase[256];
    const int t = threadIdx.x;
    const int e0 = blockIdx.x * EPB_BIN;
    const int bv = (t < NBKT) ? bcnt[t] : 0;
    sscan[t] = bv;
    if (t < NBKT) lcnt[t] = 0;
    __syncthreads();
    for (int off = 1; off < 256; off <<= 1) {
        const int u = (t >= off) ? sscan[t - off] : 0;
        __syncthreads();
        sscan[t] += u;
        __syncthreads();
    }
    sbase[t] = sscan[t] - bv;
    int dcache[16];
#pragma unroll
    for (int i = 0; i < 16; ++i) {
        const int e = e0 + i * 256 + t;
        if (e < N_EDGES) {
            const int d = dst[e];
            dcache[i] = d;
            atomicAdd(&lcnt[d >> 8], 1);
        } else dcache[i] = -1;
    }
    __syncthreads();
    for (int i = t; i < NBKT; i += 256) {
        gb[i] = sbase[i] + atomicAdd(&bfill[i], lcnt[i]);
        lf[i] = 0;
    }
    __syncthreads();
#pragma unroll
    for (int i = 0; i < 16; ++i) {
        const int e = e0 + i * 256 + t;
        if (e < N_EDGES) {
            const int d = dcache[i];
            const int bk = d >> 8;
            const int r = atomicAdd(&lf[bk], 1);
            stage[gb[bk] + r] = (unsigned int)src[e] | ((unsigned int)(d & 255) << 16);
        }
    }
}

// ---------------- per bucket scatter (bucket scan inlined) ------------------
__global__ void __launch_bounds__(256) k_bscatter2(const unsigned int* __restrict__ stage,
                                                   const int* __restrict__ bcnt,
                                                   int* __restrict__ rowp,
                                                   int* __restrict__ col) {
    __shared__ int lcnt[256];
    __shared__ int lpos[256];
    __shared__ int sexc[256];
    __shared__ int sscan[256];
    const int t = threadIdx.x;
    const int b = blockIdx.x;
    const int n0 = b << 8;
    const int bv = (t < NBKT) ? bcnt[t] : 0;
    sscan[t] = bv;
    lcnt[t] = 0;
    __syncthreads();
    for (int off = 1; off < 256; off <<= 1) {
        const int u = (t >= off) ? sscan[t - off] : 0;
        __syncthreads();
        sscan[t] += u;
        __syncthreads();
    }
    const int base = (b == 0) ? 0 : sscan[b - 1];
    const int end = sscan[b];

    for (int j = base + t; j < end; j += 256)
        atomicAdd(&lcnt[(stage[j] >> 16) & 255], 1);
    __syncthreads();
    const int v = lcnt[t];
    lpos[t] = v;
    __syncthreads();
    for (int off = 1; off < 256; off <<= 1) {
        const int u = (t >= off) ? lpos[t - off] : 0;
        __syncthreads();
        lpos[t] += u;
        __syncthreads();
    }
    sexc[t] = lpos[t] - v;
    if (n0 + t < N_NODES) rowp[n0 + t] = base + sexc[t];
    if (b == NBKT - 1 && t == 0) rowp[N_NODES] = N_EDGES;
    lcnt[t] = 0;   // reuse as fill counters
    __syncthreads();
    for (int j = base + t; j < end; j += 256) {
        const unsigned int e = stage[j];
        const int local = (int)(e >> 16) & 255;
        const int r = atomicAdd(&lcnt[local], 1);
        col[base + sexc[local] + r] = (int)(e & 0xFFFFu);
    }
}

// ---------------- fused L1: agg + gemm2, latency-optimized -------------------
// Changes vs r3: (a) 2-edge batch per lane: both col loads then 4 row-gathers
// issued before any FMA (halves dependent memory rounds); (b) 32B packed rows
// (9 dw/edge vs 13); (c) epilogue butterfly chain replaced by LDS-staged
// 16x64 * 64x6 dot on 96 threads; (d) launch_bounds(256,6) for residency.
__global__ void __launch_bounds__(256, 6) k_l1(const float* __restrict__ xph,
                                               const float* __restrict__ er_in,
                                               const int* __restrict__ rowp,
                                               const int* __restrict__ col,
                                               const float* __restrict__ W1,
                                               const float* __restrict__ b1,
                                               const float* __restrict__ Wa2,
                                               const float* __restrict__ Wr2,
                                               __half* __restrict__ hout,
                                               float* __restrict__ el,
                                               float* __restrict__ er_out) {
    __shared__ union {
        float At[16 * 28];          // agg -> gemm handoff (dead after part compute)
        float vbuf[16][72];         // gemm epilogue staging (aliases At; sync between)
    } u;
    __shared__ float part[3][16][64];
    const int t = threadIdx.x;
    const int wv = t >> 6;
    const int lane = t & 63;
    const int q = lane >> 4;            // node slot within wave
    const int ql = lane & 15;           // lane within quarter
    const int li = wv * 4 + q;          // local node 0..15
    const int nbase = blockIdx.x * 16;  // 3125 * 16 = 50000 exact
    const int n = nbase + li;

    // ---- aggregation (lane-per-edge, 2-edge batch) ----
    {
        const int jb = rowp[n], je = rowp[n + 1];
        const float4 er4 = *reinterpret_cast<const float4*>(er_in + (size_t)n * 4);
        float acc[27];
#pragma unroll
        for (int j = 0; j < 27; ++j) acc[j] = 0.f;
        float sw0 = 0.f, sw1 = 0.f, sw2 = 0.f;

        for (int e = jb + ql; e < je; e += 32) {
            const int e2 = e + 16;
            const bool v2 = (e2 < je);
            const int s1 = col[e];
            const int s2 = v2 ? col[e2] : s1;
            const float* __restrict__ r1 = xph + (size_t)s1 * 8;
            const float* __restrict__ r2 = xph + (size_t)s2 * 8;
            const float4 xa1 = *reinterpret_cast<const float4*>(r1);
            const float4 xb1 = *reinterpret_cast<const float4*>(r1 + 4);
            const float4 xa2 = *reinterpret_cast<const float4*>(r2);
            const float4 xb2 = *reinterpret_cast<const float4*>(r2 + 4);
            const float m2 = v2 ? 1.f : 0.f;
            const float w10 = __expf(lrelu(xa1.x + er4.x));
            const float w11 = __expf(lrelu(xa1.y + er4.y));
            const float w12 = __expf(lrelu(xa1.z + er4.z));
            const float w20 = __expf(lrelu(xa2.x + er4.x)) * m2;
            const float w21 = __expf(lrelu(xa2.y + er4.y)) * m2;
            const float w22 = __expf(lrelu(xa2.z + er4.z)) * m2;
            sw0 += w10 + w20; sw1 += w11 + w21; sw2 += w12 + w22;
            const float2 p10 = h2f(xa1.w), p11 = h2f(xb1.x), p12 = h2f(xb1.y),
                         p13 = h2f(xb1.z), p14 = h2f(xb1.w);
            const float2 p20 = h2f(xa2.w), p21 = h2f(xb2.x), p22 = h2f(xb2.y),
                         p23 = h2f(xb2.z), p24 = h2f(xb2.w);
            const float x1[9] = {p10.x, p10.y, p11.x, p11.y, p12.x, p12.y, p13.x, p13.y, p14.x};
            const float x2[9] = {p20.x, p20.y, p21.x, p21.y, p22.x, p22.y, p23.x, p23.y, p24.x};
#pragma unroll
            for (int k = 0; k < 9; ++k) {
                acc[0 + k]  += w10 * x1[k] + w20 * x2[k];
                acc[9 + k]  += w11 * x1[k] + w21 * x2[k];
                acc[18 + k] += w12 * x1[k] + w22 * x2[k];
            }
        }
#pragma unroll
        for (int off = 1; off < 16; off <<= 1) {
            sw0 += __shfl_xor(sw0, off);
            sw1 += __shfl_xor(sw1, off);
            sw2 += __shfl_xor(sw2, off);
#pragma unroll
            for (int j = 0; j < 27; ++j) acc[j] += __shfl_xor(acc[j], off);
        }
        if (ql == 0) {
            const bool has = (je > jb);
            const float i0 = has ? 1.f / sw0 : 0.f;
            const float i1 = has ? 1.f / sw1 : 0.f;
            const float i2 = has ? 1.f / sw2 : 0.f;
            float* __restrict__ ao = u.At + li * 28;
#pragma unroll
            for (int k = 0; k < 9; ++k) {
                ao[k] = acc[k] * i0;
                ao[9 + k] = acc[9 + k] * i1;
                ao[18 + k] = acc[18 + k] * i2;
            }
        }
    }
    __syncthreads();

    // ---- GEMM (h = wave id, c = lane) ----
    {
        const int h = wv;               // 0..3; h==3 idle for partials
        const int c = lane;
        if (h < 3) {
            float wreg[9];
#pragma unroll
            for (int k = 0; k < 9; ++k) wreg[k] = W1[k * 192 + h * 64 + c];
#pragma unroll
            for (int i = 0; i < 16; ++i) {
                const float* __restrict__ arp = u.At + i * 28 + h * 9;
                float acc = 0.f;
#pragma unroll
                for (int k = 0; k < 9; ++k) acc += arp[k] * wreg[k];
                part[h][i][c] = acc;
            }
        }
        __syncthreads();
        const float bsum = b1[c] + b1[64 + c] + b1[128 + c];
        for (int idx = t; idx < 1024; idx += 256) {
            const int i = idx >> 6, cc = idx & 63;  // cc == c (stride 256)
            const float v = part[0][i][cc] + part[1][i][cc] + part[2][i][cc] + bsum;
            hout[(size_t)(nbase + i) * 64 + cc] = __float2half(v);
            u.vbuf[i][cc] = v;           // aliases At — legal: At dead, sync above
        }
        __syncthreads();
        // 16x64 * 64x6 dot replaces four 6-stage butterfly chains
        if (t < 96) {
            const int i = t / 6, r = t % 6;
            const int h3 = (r < 3) ? r : r - 3;
            const float* __restrict__ tab = (r < 3) ? Wa2 : Wr2;
            float s = 0.f;
#pragma unroll 8
            for (int c2 = 0; c2 < 64; ++c2) s += u.vbuf[i][c2] * tab[c2 * 4 + h3];
            if (r < 3) el[(size_t)(nbase + i) * 4 + h3] = s;
            else       er_out[(size_t)(nbase + i) * 4 + h3] = s;
        }
    }
}

// ---------------- L2 aggregation v1 (verbatim; +occupancy hint) --------------
__global__ void __launch_bounds__(256, 8) k_aggw64(const __half* __restrict__ x,
                                                   const float* __restrict__ el,
                                                   const float* __restrict__ er,
                                                   const int* __restrict__ rowp,
                                                   const int* __restrict__ col,
                                                   __half* __restrict__ agg) {
    const int wv = threadIdx.x >> 6;
    const int lane = threadIdx.x & 63;
    const int n = blockIdx.x * 4 + wv;          // grid exact
    const int jb = rowp[n], je = rowp[n + 1];

    __shared__ float wbuf[4][3][68];
    __shared__ int cbuf[4][68];
    const float4 er4 = *reinterpret_cast<const float4*>(er + (size_t)n * 4);
    const int p = lane >> 5;
    const int f0 = (lane & 31) * 2;
    float a00 = 0.f, a01 = 0.f, a02 = 0.f;
    float a10 = 0.f, a11 = 0.f, a12 = 0.f;
    float sw0 = 0.f, sw1 = 0.f, sw2 = 0.f;

    for (int c0 = jb; c0 < je; c0 += 64) {
        const int cnt = min(64, je - c0);
        float w0 = 0.f, w1 = 0.f, w2 = 0.f;
        if (lane < cnt) {
            const int s = col[c0 + lane];
            cbuf[wv][lane] = s;
            const float4 e4 = *reinterpret_cast<const float4*>(el + (size_t)s * 4);
            w0 = __expf(lrelu(e4.x + er4.x));
            w1 = __expf(lrelu(e4.y + er4.y));
            w2 = __expf(lrelu(e4.z + er4.z));
            wbuf[wv][0][lane] = w0;
            wbuf[wv][1][lane] = w1;
            wbuf[wv][2][lane] = w2;
        }
        sw0 += w0; sw1 += w1; sw2 += w2;
        int e = 0;
        for (; e + 2 <= cnt; e += 2) {
            const int ei = e + p;
            const int s = cbuf[wv][ei];
            const float2 xv = __half22float2(
                *reinterpret_cast<const __half2*>(x + (size_t)s * 64 + f0));
            const float we0 = wbuf[wv][0][ei];
            const float we1 = wbuf[wv][1][ei];
            const float we2 = wbuf[wv][2][ei];
            a00 += we0 * xv.x; a01 += we1 * xv.x; a02 += we2 * xv.x;
            a10 += we0 * xv.y; a11 += we1 * xv.y; a12 += we2 * xv.y;
        }
        if (e < cnt && p == 0) {
            const int s = cbuf[wv][e];
            const float2 xv = __half22float2(
                *reinterpret_cast<const __half2*>(x + (size_t)s * 64 + f0));
            const float we0 = wbuf[wv][0][e];
            const float we1 = wbuf[wv][1][e];
            const float we2 = wbuf[wv][2][e];
            a00 += we0 * xv.x; a01 += we1 * xv.x; a02 += we2 * xv.x;
            a10 += we0 * xv.y; a11 += we1 * xv.y; a12 += we2 * xv.y;
        }
    }
    a00 += __shfl_xor(a00, 32); a01 += __shfl_xor(a01, 32); a02 += __shfl_xor(a02, 32);
    a10 += __shfl_xor(a10, 32); a11 += __shfl_xor(a11, 32); a12 += __shfl_xor(a12, 32);
#pragma unroll
    for (int off = 32; off > 0; off >>= 1) {
        sw0 += __shfl_xor(sw0, off);
        sw1 += __shfl_xor(sw1, off);
        sw2 += __shfl_xor(sw2, off);
    }
    if (lane < 32) {
        __half* __restrict__ ao = agg + (size_t)n * 192;
        if (je > jb) {
            const float i0 = 1.f / sw0, i1 = 1.f / sw1, i2 = 1.f / sw2;
            *reinterpret_cast<__half2*>(ao + f0) = __floats2half2_rn(a00 * i0, a10 * i0);
            *reinterpret_cast<__half2*>(ao + 64 + f0) = __floats2half2_rn(a01 * i1, a11 * i1);
            *reinterpret_cast<__half2*>(ao + 128 + f0) = __floats2half2_rn(a02 * i2, a12 * i2);
        } else {
            const __half2 z = __floats2half2_rn(0.f, 0.f);
            *reinterpret_cast<__half2*>(ao + f0) = z;
            *reinterpret_cast<__half2*>(ao + 64 + f0) = z;
            *reinterpret_cast<__half2*>(ao + 128 + f0) = z;
        }
    }
}

// ---------------- fused L2 GEMM (MFMA) + layer-3 features (LDS handoff) ------
// feat3p packed row (32B): {el0,el1,el2 (f32), f0..f5 (f16), pad}
__global__ void __launch_bounds__(256) k_l23(const __half* __restrict__ aggH,
                                             const __half* __restrict__ Wt,
                                             const float* __restrict__ b2,
                                             const float* __restrict__ W3,
                                             const float* __restrict__ al3,
                                             const float* __restrict__ ar3,
                                             float* __restrict__ feat3p,
                                             float* __restrict__ er3) {
    __shared__ float xl[64 * 68];
    __shared__ float Wl[64 * 6];
    __shared__ float Wal[64 * 3];
    __shared__ float Wrl[64 * 3];
    const int t = threadIdx.x;
    const int n0 = blockIdx.x * 64;             // 782 blocks; last has nvalid=16
    const int nvalid = min(64, N_NODES - n0);

    // ---- MFMA GEMM: hidden = aggH @ W2^T + b2sum, straight into LDS ----
    {
        const int wv = t >> 6;
        const int lane = t & 63;
        const int quad = lane >> 4;
        const int t16 = lane & 15;
        const int nwave = n0 + wv * 16;
        const int arow = min(nwave + t16, N_NODES - 1);
        half8 a[6];
#pragma unroll
        for (int kb = 0; kb < 6; ++kb)
            a[kb] = *reinterpret_cast<const half8*>(aggH + (size_t)arow * 192 + kb * 32 + quad * 8);
#pragma unroll
        for (int nt = 0; nt < 4; ++nt) {
            const int c = nt * 16 + t16;
            const float bs = b2[c] + b2[64 + c] + b2[128 + c];
            const __half* __restrict__ bt = Wt + (size_t)c * 192 + quad * 8;
            f32x4 acc = {0.f, 0.f, 0.f, 0.f};
#pragma unroll
            for (int kb = 0; kb < 6; ++kb) {
                const half8 bfr = *reinterpret_cast<const half8*>(bt + kb * 32);
                acc = __builtin_amdgcn_mfma_f32_16x16x32_f16(a[kb], bfr, acc, 0, 0, 0);
            }
#pragma unroll
            for (int r = 0; r < 4; ++r)
                xl[(wv * 16 + quad * 4 + r) * 68 + c] = acc[r] + bs;
        }
    }
    for (int idx = t; idx < 384; idx += 256) Wl[idx] = W3[idx];
    if (t < 192) {
        const int k = t & 63, h = t >> 6;
        Wal[k * 3 + h] = W3[k * 6 + h * 2] * al3[h * 2] + W3[k * 6 + h * 2 + 1] * al3[h * 2 + 1];
        Wrl[k * 3 + h] = W3[k * 6 + h * 2] * ar3[h * 2] + W3[k * 6 + h * 2 + 1] * ar3[h * 2 + 1];
    }
    __syncthreads();

    // ---- layer-3 packed features, two 32-row passes ----
#pragma unroll
    for (int hp = 0; hp < 2; ++hp) {
        const int i = (t >> 3) + hp * 32;
        const int slot = t & 7;
        if (i < nvalid && slot < 6) {
            float acc = 0.f;
#pragma unroll
            for (int k4 = 0; k4 < 16; ++k4) {
                const float4 xv = *reinterpret_cast<const float4*>(&xl[i * 68 + 4 * k4]);
                acc += Wl[(4 * k4 + 0) * 6 + slot] * xv.x;
                acc += Wl[(4 * k4 + 1) * 6 + slot] * xv.y;
                acc += Wl[(4 * k4 + 2) * 6 + slot] * xv.z;
                acc += Wl[(4 * k4 + 3) * 6 + slot] * xv.w;
            }
            // f16 feat at half-slots 6..11 of the 32B row
            reinterpret_cast<__half*>(feat3p + (size_t)(n0 + i) * 8)[6 + slot] = __float2half(acc);
        }
        if (t < 192) {
            const int ii = t / 6 + hp * 32, ss = t % 6;
            if (ii < nvalid) {
                const int hh = (ss < 3) ? ss : ss - 3;
                const float* __restrict__ wt = (ss < 3) ? Wal : Wrl;
                float acc = 0.f;
#pragma unroll 4
                for (int k = 0; k < 64; ++k) acc += xl[ii * 68 + k] * wt[k * 3 + hh];
                if (ss < 3) feat3p[(size_t)(n0 + ii) * 8 + hh] = acc;   // el3 f32 at 0..2
                else        er3[(size_t)(n0 + ii) * 4 + hh] = acc;
            }
        }
    }
}

// ---------------- layer-3 aggregation: 2-edge batch, packed rows -------------
__global__ void __launch_bounds__(256, 8) k_agg3(const float* __restrict__ feat3p,
                                                 const float* __restrict__ er3,
                                                 const float* __restrict__ b3,
                                                 const int* __restrict__ rowp,
                                                 const int* __restrict__ col,
                                                 float* __restrict__ out) {
    const int tid = threadIdx.x;
    const int wv = tid >> 6;
    const int lane = tid & 63;
    const int q = lane >> 4;
    const int ql = lane & 15;
    const int n = (blockIdx.x * 4 + wv) * 4 + q;   // grid exact: 3125*16 = 50000
    const int jb = rowp[n], je = rowp[n + 1];
    const float4 er4 = *reinterpret_cast<const float4*>(er3 + (size_t)n * 4);

    float acc[6];
#pragma unroll
    for (int j = 0; j < 6; ++j) acc[j] = 0.f;
    float sw0 = 0.f, sw1 = 0.f, sw2 = 0.f;

    for (int e = jb + ql; e < je; e += 32) {
        const int e2 = e + 16;
        const bool v2 = (e2 < je);
        const int s1 = col[e];
        const int s2 = v2 ? col[e2] : s1;
        const float* __restrict__ r1 = feat3p + (size_t)s1 * 8;
        const float* __restrict__ r2 = feat3p + (size_t)s2 * 8;
        const float4 fa1 = *reinterpret_cast<const float4*>(r1);   // el0..2, f01
        const float2 fb1 = *reinterpret_cast<const float2*>(r1 + 4); // f23, f45
        const float4 fa2 = *reinterpret_cast<const float4*>(r2);
        const float2 fb2 = *reinterpret_cast<const float2*>(r2 + 4);
        const float m2 = v2 ? 1.f : 0.f;
        const float w10 = __expf(lrelu(fa1.x + er4.x));
        const float w11 = __expf(lrelu(fa1.y + er4.y));
        const float w12 = __expf(lrelu(fa1.z + er4.z));
        const float w20 = __expf(lrelu(fa2.x + er4.x)) * m2;
        const float w21 = __expf(lrelu(fa2.y + er4.y)) * m2;
        const float w22 = __expf(lrelu(fa2.z + er4.z)) * m2;
        sw0 += w10 + w20; sw1 += w11 + w21; sw2 += w12 + w22;
        const float2 f01a = h2f(fa1.w), f23a = h2f(fb1.x), f45a = h2f(fb1.y);
        const float2 f01b = h2f(fa2.w), f23b = h2f(fb2.x), f45b = h2f(fb2.y);
        acc[0] += w10 * f01a.x + w20 * f01b.x;
        acc[1] += w10 * f01a.y + w20 * f01b.y;
        acc[2] += w11 * f23a.x + w21 * f23b.x;
        acc[3] += w11 * f23a.y + w21 * f23b.y;
        acc[4] += w12 * f45a.x + w22 * f45b.x;
        acc[5] += w12 * f45a.y + w22 * f45b.y;
    }
#pragma unroll
    for (int off = 1; off < 16; off <<= 1) {
        sw0 += __shfl_xor(sw0, off);
        sw1 += __shfl_xor(sw1, off);
        sw2 += __shfl_xor(sw2, off);
#pragma unroll
        for (int j = 0; j < 6; ++j) acc[j] += __shfl_xor(acc[j], off);
    }
    if (ql == 0) {
        const bool has = (je > jb);
        const float i0 = has ? 1.f / sw0 : 0.f;
        const float i1 = has ? 1.f / sw1 : 0.f;
        const float i2 = has ? 1.f / sw2 : 0.f;
        const float o0 = acc[0] * i0 + acc[2] * i1 + acc[4] * i2 + b3[0] + b3[2] + b3[4];
        const float o1 = acc[1] * i0 + acc[3] * i1 + acc[5] * i2 + b3[1] + b3[3] + b3[5];
        *reinterpret_cast<float2*>(out + (size_t)n * 2) = make_float2(o0, o1);
    }
}

extern "C" void kernel_launch(void* const* d_in, const int* in_sizes, int n_in,
                              void* d_out, int out_size, void* d_ws, size_t ws_size,
                              hipStream_t stream) {
    const float* feats = (const float*)d_in[0];
    const int* src = (const int*)d_in[1];
    const int* dst = (const int*)d_in[2];
    const float* W1 = (const float*)d_in[3];
    const float* al1 = (const float*)d_in[4];
    const float* ar1 = (const float*)d_in[5];
    const float* b1 = (const float*)d_in[6];
    const float* W2 = (const float*)d_in[7];
    const float* al2 = (const float*)d_in[8];
    const float* ar2 = (const float*)d_in[9];
    const float* b2 = (const float*)d_in[10];
    const float* W3 = (const float*)d_in[11];
    const float* al3 = (const float*)d_in[12];
    const float* ar3 = (const float*)d_in[13];
    const float* b3 = (const float*)d_in[14];
    float* out = (float*)d_out;

    char* ws = (char*)d_ws;
    size_t off = 0;
    auto alloc = [&](size_t bytes) {
        void* p = ws + off;
        off += (bytes + 255) & ~(size_t)255;
        return p;
    };
    __half* aggH = (__half*)alloc((size_t)N_NODES * 192 * 2);    // L2 agg fp16 [N][192]
    __half* hbufH = (__half*)alloc((size_t)N_NODES * 64 * 2);    // fp16 L1 hidden
    float* xph = (float*)alloc((size_t)N_NODES * 8 * 4);         // packed el1(f32)+x(f16)
    float* el = (float*)alloc((size_t)N_NODES * 4 * 4);
    float* er = (float*)alloc((size_t)N_NODES * 4 * 4);
    int* bcnt = (int*)alloc(512 * 4);                            // bcnt[256] + bfill[256]
    int* bfill = bcnt + 256;
    int* rowp = (int*)alloc((size_t)(N_NODES + 1) * 4);
    int* col = (int*)alloc((size_t)N_EDGES * 4);
    unsigned int* stage = (unsigned int*)alloc((size_t)N_EDGES * 4);
    __half* Wt16 = (__half*)alloc((size_t)64 * 192 * 2);         // 24 KB fp16 W2^T
    float* Wa2 = (float*)alloc(256 * 4);
    float* Wr2 = (float*)alloc(256 * 4);
    float* feat3p = (float*)alloc((size_t)N_NODES * 8 * 4);      // packed el3(f32)+feat(f16)
    (void)ws_size;

    const int ab = N_NODES / 4;             // k_aggw64: 4 waves/block
    const int qb = N_NODES / 16;            // 16 nodes/block kernels
    const int lb = (N_NODES + 63) / 64;     // k_l23: 64 nodes/block

    // ---- CSR build + front prep ----
    hipMemsetAsync(bcnt, 0, 512 * 4, stream);
    k_front<<<NB_BIN + NB_EL + NB_PW + 1, 256, 0, stream>>>(
        dst, bcnt, feats, W1, al1, ar1, xph, er, W2, Wt16, al2, ar2, Wa2, Wr2);
    k_bin<<<NB_BIN, 256, 0, stream>>>(src, dst, bcnt, bfill, stage);
    k_bscatter2<<<NBKT, 256, 0, stream>>>(stage, bcnt, rowp, col);

    // ---- layer 1 (agg + GEMM fused) ----
    k_l1<<<qb, 256, 0, stream>>>(xph, er, rowp, col, W1, b1, Wa2, Wr2, hbufH, el, er);

    // ---- layer 2 aggregation ----
    k_aggw64<<<ab, 256, 0, stream>>>(hbufH, el, er, rowp, col, aggH);

    // ---- layer-2 GEMM + layer-3 features (fused) ----
    k_l23<<<lb, 256, 0, stream>>>(aggH, Wt16, b2, W3, al3, ar3, feat3p, er);

    // ---- layer 3 aggregation ----
    k_agg3<<<qb, 256, 0, stream>>>(feat3p, er, b3, rowp, col, out);
}